// Round 11
// baseline (39.458 us; speedup 1.0000x reference)
//
#include <hip/hip_runtime.h>

// DICE multi-class loss (single fused kernel, fence-free handoff).
//   output: [B=16, C=8, H=512, W=512] fp32
//   mask:   [B=16, H=512, W=512] int32 (labels 0..7)
// loss = 1 - sum_{b,c} dice(b,c) / (B*B),  dice = 2*(num+eps)/(den1+den2+eps)
//
// Journal:
// R4: 8 waves/CU latency-bound. R5: NT + DPP reduce -> 30.66us.
// R6: per-block __threadfence (L2 inv/wb storm) = 6x disaster. NEVER fence
//     per-block in a streaming kernel.
// R8 A/B: NT loads help +5%. R9 BEST: BPB=64, 16 waves/CU -> 29.58us.
// R10: channel-sequential streams regressed (31.4) - interleave is fine.
// R11: fuse final reduction WITHOUT fences: agent-scope atomicAdd into 384
//     accumulators (memory-side coherence point, no cache flush) + ticket;
//     last block reads accs with relaxed agent atomic loads. __syncthreads
//     drains vmcnt -> adds complete before ticket. Saves launch + 1-block
//     stage-2 (~3us). FP-order jitter ~1e-6 << 1.7e-2 threshold.

#define BB 16
#define CC 8
#define HWPIX (512 * 512)
#define HW4 (HWPIX / 4)      // 65536 float4-quads per plane
#define BPB 64               // partial-blocks per batch image
#define QPB (HW4 / BPB)      // 1024 quads per block -> 4 iters/thread
#define NBLOCKS (BB * BPB)   // 1024 blocks = 4/CU, 16 waves/CU (R9-proven)
#define NACC (3 * BB * CC)   // 384 accumulators

typedef float f32x4 __attribute__((ext_vector_type(4)));
typedef int i32x4 __attribute__((ext_vector_type(4)));

// ---- DPP wave64 sum (VALU pipe only, no DS ops); total lands in lane 63 ----
template <int CTRL>
__device__ __forceinline__ float dpp_add(float x) {
    int yi = __builtin_amdgcn_update_dpp(0, __float_as_int(x), CTRL, 0xf, 0xf, true);
    return x + __int_as_float(yi);
}
__device__ __forceinline__ float wave_sum63(float x) {
    x = dpp_add<0x111>(x);   // row_shr:1
    x = dpp_add<0x112>(x);   // row_shr:2
    x = dpp_add<0x114>(x);   // row_shr:4
    x = dpp_add<0x118>(x);   // row_shr:8
    x = dpp_add<0x142>(x);   // row_bcast:15
    x = dpp_add<0x143>(x);   // row_bcast:31
    return x;
}

__global__ __launch_bounds__(256) void dice_fused(const float* __restrict__ out,
                                                  const int* __restrict__ mask,
                                                  float* __restrict__ acc,
                                                  unsigned* __restrict__ cnt,
                                                  float* __restrict__ loss) {
    const int b = blockIdx.x / BPB;
    const int blk = blockIdx.x % BPB;
    const f32x4* __restrict__ ov = (const f32x4*)(out + (size_t)b * CC * HWPIX);
    const i32x4* __restrict__ mv = (const i32x4*)(mask + (size_t)b * HWPIX);

    float num[CC], d1[CC], d2[CC];
#pragma unroll
    for (int c = 0; c < CC; ++c) { num[c] = 0.f; d1[c] = 0.f; d2[c] = 0.f; }

    const int q0 = blk * QPB;
#pragma unroll 2
    for (int q = q0 + threadIdx.x; q < q0 + QPB; q += 256) {
        const i32x4 m = __builtin_nontemporal_load(&mv[q]);
        f32x4 v[CC];
#pragma unroll
        for (int c = 0; c < CC; ++c) v[c] = __builtin_nontemporal_load(&ov[c * HW4 + q]);
#pragma unroll
        for (int c = 0; c < CC; ++c) {
            d1[c] += v[c].x * v[c].x + v[c].y * v[c].y + v[c].z * v[c].z + v[c].w * v[c].w;
            float hx = (m.x == c) ? 1.f : 0.f;
            float hy = (m.y == c) ? 1.f : 0.f;
            float hz = (m.z == c) ? 1.f : 0.f;
            float hw = (m.w == c) ? 1.f : 0.f;
            num[c] += hx * v[c].x + hy * v[c].y + hz * v[c].z + hw * v[c].w;
            d2[c] += hx + hy + hz + hw;
        }
    }

    const int lane = threadIdx.x & 63;
    const int wid = threadIdx.x >> 6;
    __shared__ float red[4][24];
#pragma unroll
    for (int c = 0; c < CC; ++c) {
        float a0 = wave_sum63(num[c]);
        float a1 = wave_sum63(d1[c]);
        float a2 = wave_sum63(d2[c]);
        if (lane == 63) {
            red[wid][0 * 8 + c] = a0;
            red[wid][1 * 8 + c] = a1;
            red[wid][2 * 8 + c] = a2;
        }
    }
    __syncthreads();
    if (threadIdx.x < 24) {
        const int k = threadIdx.x;       // k = qy*8 + c
        const int qy = k >> 3;
        const int c = k & 7;
        float s = red[0][k] + red[1][k] + red[2][k] + red[3][k];
        // agent-scope FP atomic: executed at memory-side coherence point,
        // no cache flush. acc layout: [qy][b][c]
        atomicAdd(&acc[(qy * BB + b) * CC + c], s);
    }

    // ---- fence-free last-block-done handoff ----
    __syncthreads();                 // compiler emits s_waitcnt vmcnt(0) before
                                     // s_barrier -> our atomics are complete &
                                     // globally visible (memory-side) here
    __shared__ unsigned tk;
    if (threadIdx.x == 0) tk = atomicAdd(cnt, 1u);
    __syncthreads();

    if (tk == NBLOCKS - 1) {         // all 256 threads of last block enter
        const int t = threadIdx.x;
        float dice = 0.f;
        if (t < 128) {               // t = b*8+c
            float n = __hip_atomic_load(&acc[0 * 128 + t], __ATOMIC_RELAXED,
                                        __HIP_MEMORY_SCOPE_AGENT);
            float a = __hip_atomic_load(&acc[1 * 128 + t], __ATOMIC_RELAXED,
                                        __HIP_MEMORY_SCOPE_AGENT);
            float o = __hip_atomic_load(&acc[2 * 128 + t], __ATOMIC_RELAXED,
                                        __HIP_MEMORY_SCOPE_AGENT);
            const float eps = 1e-7f;
            dice = 2.f * (n + eps) / (a + o + eps);
        }
        float x = wave_sum63(dice);  // waves 2,3 reduce zeros - harmless
        __shared__ float sm2[4];
        if ((t & 63) == 63) sm2[t >> 6] = x;
        __syncthreads();
        if (t == 0) loss[0] = 1.f - (sm2[0] + sm2[1]) / ((float)BB * (float)BB);
    }
}

extern "C" void kernel_launch(void* const* d_in, const int* in_sizes, int n_in,
                              void* d_out, int out_size, void* d_ws, size_t ws_size,
                              hipStream_t stream) {
    const float* out_probs = (const float*)d_in[0];
    const int* mask = (const int*)d_in[1];
    float* acc = (float*)d_ws;                  // 384 floats
    unsigned* cnt = (unsigned*)(acc + NACC);    // 1 uint right after
    float* loss = (float*)d_out;

    // zero accumulators + ticket each call (graph-capture-safe, deterministic)
    hipMemsetAsync(d_ws, 0, (NACC + 1) * sizeof(float), stream);
    dice_fused<<<NBLOCKS, 256, 0, stream>>>(out_probs, mask, acc, cnt, loss);
}

// Round 12
// 29.489 us; speedup vs baseline: 1.3381x; 1.3381x over previous
//
#include <hip/hip_runtime.h>

// DICE multi-class loss.
//   output: [B=16, C=8, H=512, W=512] fp32
//   mask:   [B=16, H=512, W=512] int32 (labels 0..7)
// loss = 1 - sum_{b,c} dice(b,c) / (B*B),  dice = 2*(num+eps)/(den1+den2+eps)
//
// Journal (final state = R9, the measured optimum):
// R4: 8 waves/CU latency-bound (37us).
// R5: NT loads + DPP VALU wave-reduce (no DS pipe) -> 30.66us.
// R6: fused w/ per-block __threadfence = L2 inv/wb storm -> 188us. NEVER.
// R8: A/B: NT loads help +5% (plain 32.3 vs NT 30.7).
// R9: BPB=64 -> 1024 blocks, 16 waves/CU, 4 iters/thread -> 29.58us. BEST.
// R10: channel-sequential streams -> 31.4us (interleaved 9-stream is fine).
// R11: fence-free atomic+ticket fusion -> 39.5us (in-graph memset node +
//      1024-deep ticket serialization). Two-kernel structure is best.
// Decomposition at 29.58us: stage-1 151MB @ ~5.7 TB/s = 26.5us (90% of the
// 6.29 TB/s copy ceiling, part L3-served), stage-2 + launch gap ~3us.

#define BB 16
#define CC 8
#define HWPIX (512 * 512)
#define HW4 (HWPIX / 4)      // 65536 float4-quads per plane
#define BPB 64               // partial-blocks per batch image
#define QPB (HW4 / BPB)      // 1024 quads per block -> 4 iters/thread
#define NBLOCKS (BB * BPB)   // 1024 blocks = 4/CU, 16 waves/CU

typedef float f32x4 __attribute__((ext_vector_type(4)));
typedef int i32x4 __attribute__((ext_vector_type(4)));

// ---- DPP wave64 sum (VALU pipe only, no DS ops); total lands in lane 63 ----
template <int CTRL>
__device__ __forceinline__ float dpp_add(float x) {
    int yi = __builtin_amdgcn_update_dpp(0, __float_as_int(x), CTRL, 0xf, 0xf, true);
    return x + __int_as_float(yi);
}
__device__ __forceinline__ float wave_sum63(float x) {
    x = dpp_add<0x111>(x);   // row_shr:1
    x = dpp_add<0x112>(x);   // row_shr:2
    x = dpp_add<0x114>(x);   // row_shr:4
    x = dpp_add<0x118>(x);   // row_shr:8
    x = dpp_add<0x142>(x);   // row_bcast:15
    x = dpp_add<0x143>(x);   // row_bcast:31
    return x;
}

__global__ __launch_bounds__(256) void dice_partial(const float* __restrict__ out,
                                                    const int* __restrict__ mask,
                                                    float* __restrict__ ws) {
    const int b = blockIdx.x / BPB;
    const int blk = blockIdx.x % BPB;
    const f32x4* __restrict__ ov = (const f32x4*)(out + (size_t)b * CC * HWPIX);
    const i32x4* __restrict__ mv = (const i32x4*)(mask + (size_t)b * HWPIX);

    float num[CC], d1[CC], d2[CC];
#pragma unroll
    for (int c = 0; c < CC; ++c) { num[c] = 0.f; d1[c] = 0.f; d2[c] = 0.f; }

    const int q0 = blk * QPB;
#pragma unroll 2
    for (int q = q0 + threadIdx.x; q < q0 + QPB; q += 256) {
        const i32x4 m = __builtin_nontemporal_load(&mv[q]);
        f32x4 v[CC];
#pragma unroll
        for (int c = 0; c < CC; ++c) v[c] = __builtin_nontemporal_load(&ov[c * HW4 + q]);
#pragma unroll
        for (int c = 0; c < CC; ++c) {
            d1[c] += v[c].x * v[c].x + v[c].y * v[c].y + v[c].z * v[c].z + v[c].w * v[c].w;
            float hx = (m.x == c) ? 1.f : 0.f;
            float hy = (m.y == c) ? 1.f : 0.f;
            float hz = (m.z == c) ? 1.f : 0.f;
            float hw = (m.w == c) ? 1.f : 0.f;
            num[c] += hx * v[c].x + hy * v[c].y + hz * v[c].z + hw * v[c].w;
            d2[c] += hx + hy + hz + hw;
        }
    }

    const int lane = threadIdx.x & 63;
    const int wid = threadIdx.x >> 6;
    __shared__ float red[4][24];
#pragma unroll
    for (int c = 0; c < CC; ++c) {
        float a0 = wave_sum63(num[c]);
        float a1 = wave_sum63(d1[c]);
        float a2 = wave_sum63(d2[c]);
        if (lane == 63) {
            red[wid][0 * 8 + c] = a0;
            red[wid][1 * 8 + c] = a1;
            red[wid][2 * 8 + c] = a2;
        }
    }
    __syncthreads();
    if (threadIdx.x < 24) {
        const int k = threadIdx.x;       // k = qy*8 + c
        const int qy = k >> 3;
        const int c = k & 7;
        float s = red[0][k] + red[1][k] + red[2][k] + red[3][k];
        // partial layout: ws[((qy*BB + b)*CC + c)*BPB + blk]
        ws[((qy * BB + b) * CC + c) * BPB + blk] = s;
    }
}

// 1024 threads: 8 threads per (b,c) pair, 2 f32x4 loads per quantity.
__global__ __launch_bounds__(1024) void dice_final(const float* __restrict__ ws,
                                                   float* __restrict__ out) {
    const int t = threadIdx.x;
    const int g = t >> 3;        // (b,c) group 0..127
    const int sub = t & 7;
    const int b = g >> 3;
    const int c = g & 7;

    float acc[3] = {0.f, 0.f, 0.f};   // num, d1, d2
#pragma unroll
    for (int qy = 0; qy < 3; ++qy) {
        const f32x4* p = (const f32x4*)(ws + ((qy * BB + b) * CC + c) * BPB);
#pragma unroll
        for (int i = 0; i < BPB / (8 * 4); ++i) {   // 2 f32x4 per thread
            f32x4 v = p[sub + i * 8];
            acc[qy] += v.x + v.y + v.z + v.w;
        }
    }
#pragma unroll
    for (int qy = 0; qy < 3; ++qy) {
#pragma unroll
        for (int o = 4; o > 0; o >>= 1) acc[qy] += __shfl_down(acc[qy], o, 8);
    }

    __shared__ float sm[128];
    __shared__ float sm2[2];
    if (sub == 0) {
        const float eps = 1e-7f;
        sm[g] = 2.f * (acc[0] + eps) / (acc[1] + acc[2] + eps);
    }
    __syncthreads();
    if (t < 128) {
        float x = wave_sum63(sm[t]);
        if ((t & 63) == 63) sm2[t >> 6] = x;
    }
    __syncthreads();
    if (t == 0) out[0] = 1.f - (sm2[0] + sm2[1]) / ((float)BB * (float)BB);
}

extern "C" void kernel_launch(void* const* d_in, const int* in_sizes, int n_in,
                              void* d_out, int out_size, void* d_ws, size_t ws_size,
                              hipStream_t stream) {
    const float* out_probs = (const float*)d_in[0];
    const int* mask = (const int*)d_in[1];
    float* ws = (float*)d_ws;    // 3*16*8*64 floats = 96 KiB
    float* loss = (float*)d_out;

    dice_partial<<<NBLOCKS, 256, 0, stream>>>(out_probs, mask, ws);
    dice_final<<<1, 1024, 0, stream>>>(ws, loss);
}